// Round 4
// baseline (574.152 us; speedup 1.0000x reference)
//
#include <hip/hip_runtime.h>
#include <hip/hip_bf16.h>
#include <math.h>

// Problem constants
#define LSEQ 2048
#define DMODEL 1024
#define DINNER 2048
#define DSTATE 16
#define DCONV 4
#define DTRANK 64
#define RPROJ 96   // DTRANK + 2*DSTATE

// Chunked-scan decomposition
#define CHUNK 32
#define NCHUNK (LSEQ / CHUNK)   // 64

typedef __attribute__((ext_vector_type(8))) short bf16x8;
typedef __attribute__((ext_vector_type(4))) float f32x4;

__device__ __forceinline__ float softplusf(float x) {
    return (x > 20.f) ? x : log1pf(__expf(x));
}
__device__ __forceinline__ float siluf(float x) {
    return x / (1.f + __expf(-x));
}
// f32 -> bf16 RTNE
__device__ __forceinline__ short f2bf(float f) {
    union { float f; unsigned u; } v; v.f = f;
    unsigned r = v.u + 0x7FFFu + ((v.u >> 16) & 1u);
    return (short)(r >> 16);
}
// bf16 -> f32
__device__ __forceinline__ float bf2f(short h) {
    union { unsigned u; float f; } v;
    v.u = ((unsigned)(unsigned short)h) << 16;
    return v.f;
}

// ---------------- f32 -> bf16 bulk convert (n % 2048 == 0) ----------------
__global__ __launch_bounds__(256) void cvt_bf16(
    const float* __restrict__ s, short* __restrict__ d, int n)
{
    const int i = (blockIdx.x * 256 + threadIdx.x) * 8;
    if (i >= n) return;
    const float4 a = *(const float4*)(s + i);
    const float4 b = *(const float4*)(s + i + 4);
    alignas(16) short h[8];
    h[0] = f2bf(a.x); h[1] = f2bf(a.y); h[2] = f2bf(a.z); h[3] = f2bf(a.w);
    h[4] = f2bf(b.x); h[5] = f2bf(b.y); h[6] = f2bf(b.z); h[7] = f2bf(b.w);
    *(uint4*)(d + i) = *(const uint4*)h;
}

// ---------------- LayerNorm: one block per row; f32 or bf16 out ----------
__global__ __launch_bounds__(256) void ln_kernel(
    const float* __restrict__ x, const float* __restrict__ w,
    const float* __restrict__ b, float* __restrict__ outf,
    short* __restrict__ outb)
{
    __shared__ float s1[256], s2[256];
    const int row = blockIdx.x;
    const int tid = threadIdx.x;
    const float* xr = x + (size_t)row * DMODEL;
    float v[4];
    float s = 0.f, sq = 0.f;
#pragma unroll
    for (int k = 0; k < 4; k++) {
        v[k] = xr[k * 256 + tid];
        s += v[k];
        sq += v[k] * v[k];
    }
    s1[tid] = s; s2[tid] = sq;
    __syncthreads();
    for (int off = 128; off > 0; off >>= 1) {
        if (tid < off) { s1[tid] += s1[tid + off]; s2[tid] += s2[tid + off]; }
        __syncthreads();
    }
    const float mu = s1[0] * (1.f / DMODEL);
    const float var = s2[0] * (1.f / DMODEL) - mu * mu;
    const float rstd = rsqrtf(var + 1e-5f);
#pragma unroll
    for (int k = 0; k < 4; k++) {
        const int i = k * 256 + tid;
        const float o = (v[k] - mu) * rstd * w[i] + b[i];
        if (outf) outf[(size_t)row * DMODEL + i] = o;
        if (outb) outb[(size_t)row * DMODEL + i] = f2bf(o);
    }
}

// ---------------- bf16 MFMA NT GEMM: C[M,N] = A[M,K] * W[N,K]^T -----------
// 128-row tile, BN_T in {64,128}, BK=32, global_load_lds staging.
// MODE 0: f32 store            MODE 1: f32 softplus(.+bias[n])
// MODE 2: f32 (. + resid)      MODE 3: bf16 store only
// MODE 4: f32 store + bf16 dual store
template<int BN_T, int MODE>
__global__ __launch_bounds__(256) void gemm_mfma(
    const short* __restrict__ A, int lda,   // [M,lda] bf16 (uses cols 0..K-1)
    const short* __restrict__ W, int ldw,   // [N,ldw] bf16
    float* __restrict__ Cf, short* __restrict__ Cb, int ldc,
    int M, int N, int K,
    const float* __restrict__ bias,
    const float* __restrict__ resid)
{
    constexpr int BK = 32;
    constexpr int HN = BN_T / 2;      // wave col span
    constexpr int NJ = BN_T / 32;     // 16x16 frags per wave in N
    constexpr int WISS = (BN_T * BK * 2) / 4096;  // W staging issues (1 or 2)
    __shared__ alignas(16) short As[128 * BK];
    __shared__ alignas(16) short Ws[BN_T * BK];

    const int tid = threadIdx.x;
    const int lane = tid & 63;
    const int w = tid >> 6;
    const int wr = w >> 1, wc = w & 1;
    const int row0 = blockIdx.y * 128;
    const int col0 = blockIdx.x * BN_T;

    const int srow = tid >> 2;            // staging row (0..63)
    const int skch = (tid & 3) * 8;       // staging k element offset

    f32x4 acc[4][NJ];
#pragma unroll
    for (int i = 0; i < 4; i++)
#pragma unroll
        for (int j = 0; j < NJ; j++) acc[i][j] = (f32x4)0.f;

    const int lrow = lane & 15;
    const int lk = (lane >> 4) * 8;

    for (int kt = 0; kt < K; kt += BK) {
        __syncthreads();
        // stage A tile: 128 rows x 32 k (bf16), 2 issues of 4 KB
#pragma unroll
        for (int j = 0; j < 2; j++) {
            const short* gp = A + (size_t)(row0 + j * 64 + srow) * lda + kt + skch;
            short* lp = As + j * 2048 + w * 512;   // wave-uniform LDS base
            __builtin_amdgcn_global_load_lds(
                (const __attribute__((address_space(1))) void*)gp,
                (__attribute__((address_space(3))) void*)lp, 16, 0, 0);
        }
        // stage W tile
#pragma unroll
        for (int j = 0; j < WISS; j++) {
            const int wrow = col0 + j * 64 + srow;
            const short* gp = W + (size_t)wrow * ldw + kt + skch;
            short* lp = Ws + j * 2048 + w * 512;
            if (wrow < N)
                __builtin_amdgcn_global_load_lds(
                    (const __attribute__((address_space(1))) void*)gp,
                    (__attribute__((address_space(3))) void*)lp, 16, 0, 0);
        }
        __syncthreads();

        bf16x8 af[4], bfr[NJ];
#pragma unroll
        for (int i = 0; i < 4; i++)
            af[i] = *(const bf16x8*)&As[(wr * 64 + i * 16 + lrow) * BK + lk];
#pragma unroll
        for (int j = 0; j < NJ; j++)
            bfr[j] = *(const bf16x8*)&Ws[(wc * HN + j * 16 + lrow) * BK + lk];
#pragma unroll
        for (int i = 0; i < 4; i++)
#pragma unroll
            for (int j = 0; j < NJ; j++)
                acc[i][j] = __builtin_amdgcn_mfma_f32_16x16x32_bf16(
                    af[i], bfr[j], acc[i][j], 0, 0, 0);
    }

    // epilogue: C/D layout col=lane&15, row=(lane>>4)*4+reg
    const int rbase = row0 + wr * 64;
    const int cbase = col0 + wc * HN;
#pragma unroll
    for (int i = 0; i < 4; i++) {
#pragma unroll
        for (int j = 0; j < NJ; j++) {
            const int gcol = cbase + j * 16 + lrow;
            if (gcol < N) {
#pragma unroll
                for (int r = 0; r < 4; r++) {
                    const int grow = rbase + i * 16 + (lane >> 4) * 4 + r;
                    float v = acc[i][j][r];
                    if (MODE == 1) v = softplusf(v + bias[gcol]);
                    if (MODE == 2) v += resid[(size_t)grow * ldc + gcol];
                    if (MODE == 3) {
                        Cb[(size_t)grow * ldc + gcol] = f2bf(v);
                    } else {
                        Cf[(size_t)grow * ldc + gcol] = v;
                        if (MODE == 4) Cb[(size_t)grow * ldc + gcol] = f2bf(v);
                    }
                }
            }
        }
    }
}

// ---------------- Causal depthwise conv (k=4) + bias + silu ----------------
// reads x-half of xz_bf [L, 2*DINNER] bf16, writes xc_bf [L, DINNER] bf16
__global__ __launch_bounds__(256) void conv_silu_kernel(
    const short* __restrict__ xzb, const float* __restrict__ cw,
    const float* __restrict__ cb, short* __restrict__ xcb)
{
    const int g = blockIdx.x * 256 + threadIdx.x;
    const int c = g & (DINNER - 1);
    const int t = g >> 11;
    float acc = cb[c];
#pragma unroll
    for (int k = 0; k < DCONV; k++) {
        const int tt = t - (DCONV - 1) + k;
        if (tt >= 0)
            acc += bf2f(xzb[(size_t)tt * (2 * DINNER) + c]) * cw[c * DCONV + k];
    }
    xcb[(size_t)t * DINNER + c] = f2bf(siluf(acc));
}

// ============ Chunked selective scan ============
// h_t = exp(dt_t*a_n) h_{t-1} + dt_t*xc_t*B_t[n];  y_t = <h_t, C_t>
__global__ __launch_bounds__(256) void scan_pass1(
    const float* __restrict__ dt,    // [L, DINNER] f32
    const short* __restrict__ xcb,   // [L, DINNER] bf16
    const float* __restrict__ dbl,   // [L, RPROJ] f32
    const float* __restrict__ A_log,
    float* __restrict__ S,           // [NCHUNK][DSTATE][DINNER]
    float* __restrict__ sumdt)       // [NCHUNK][DINNER]
{
    const int e = blockIdx.x * 256 + threadIdx.x;
    const int c = blockIdx.y;
    float a[DSTATE];
#pragma unroll
    for (int n = 0; n < DSTATE; n++) a[n] = -__expf(A_log[(size_t)e * DSTATE + n]);
    float h[DSTATE];
#pragma unroll
    for (int n = 0; n < DSTATE; n++) h[n] = 0.f;
    float sd = 0.f;

    __shared__ float sBC[CHUNK][32];
    for (int i = threadIdx.x; i < CHUNK * 32; i += 256) {
        const int tl = i >> 5, j = i & 31;
        sBC[tl][j] = dbl[(size_t)(c * CHUNK + tl) * RPROJ + DTRANK + j];
    }
    __syncthreads();

    for (int tl = 0; tl < CHUNK; tl++) {
        const int t = c * CHUNK + tl;
        const float dtv = dt[(size_t)t * DINNER + e];
        const float du = dtv * bf2f(xcb[(size_t)t * DINNER + e]);
        sd += dtv;
#pragma unroll
        for (int n = 0; n < DSTATE; n++) {
            const float dA = __expf(dtv * a[n]);
            h[n] = dA * h[n] + du * sBC[tl][n];
        }
    }
    sumdt[(size_t)c * DINNER + e] = sd;
#pragma unroll
    for (int n = 0; n < DSTATE; n++)
        S[((size_t)c * DSTATE + n) * DINNER + e] = h[n];
}

__global__ __launch_bounds__(256) void scan_pass2(
    const float* __restrict__ A_log,
    const float* __restrict__ sumdt,
    float* __restrict__ S)
{
    const int idx = blockIdx.x * 256 + threadIdx.x;
    const int e = idx & (DINNER - 1);
    const int n = idx >> 11;
    const float a = -__expf(A_log[(size_t)e * DSTATE + n]);
    float H = 0.f;
    for (int c = 0; c < NCHUNK; c++) {
        const size_t off = ((size_t)c * DSTATE + n) * DINNER + e;
        const float tmp = S[off];
        S[off] = H;
        const float P = __expf(a * sumdt[(size_t)c * DINNER + e]);
        H = P * H + tmp;
    }
}

// pass3: seeded chunk-local scan -> gated y (bf16 for out_proj)
__global__ __launch_bounds__(256) void scan_pass3(
    const float* __restrict__ dt,
    const short* __restrict__ xcb,
    const float* __restrict__ dbl,
    const short* __restrict__ xzb,   // z at cols DINNER.. (bf16)
    const float* __restrict__ A_log,
    const float* __restrict__ Dp,
    const float* __restrict__ S,
    short* __restrict__ yb)
{
    const int e = blockIdx.x * 256 + threadIdx.x;
    const int c = blockIdx.y;
    float a[DSTATE];
#pragma unroll
    for (int n = 0; n < DSTATE; n++) a[n] = -__expf(A_log[(size_t)e * DSTATE + n]);
    float h[DSTATE];
#pragma unroll
    for (int n = 0; n < DSTATE; n++)
        h[n] = S[((size_t)c * DSTATE + n) * DINNER + e];
    const float dskip = Dp[e];

    __shared__ float sBC[CHUNK][32];
    for (int i = threadIdx.x; i < CHUNK * 32; i += 256) {
        const int tl = i >> 5, j = i & 31;
        sBC[tl][j] = dbl[(size_t)(c * CHUNK + tl) * RPROJ + DTRANK + j];
    }
    __syncthreads();

    for (int tl = 0; tl < CHUNK; tl++) {
        const int t = c * CHUNK + tl;
        const float dtv = dt[(size_t)t * DINNER + e];
        const float xcv = bf2f(xcb[(size_t)t * DINNER + e]);
        const float du = dtv * xcv;
        float yv = 0.f;
#pragma unroll
        for (int n = 0; n < DSTATE; n++) {
            const float dA = __expf(dtv * a[n]);
            h[n] = dA * h[n] + du * sBC[tl][n];
            yv += h[n] * sBC[tl][16 + n];
        }
        const float zv = bf2f(xzb[(size_t)t * (2 * DINNER) + DINNER + e]);
        yv = (yv + xcv * dskip) * siluf(zv);
        yb[(size_t)t * DINNER + e] = f2bf(yv);
    }
}

extern "C" void kernel_launch(void* const* d_in, const int* in_sizes, int n_in,
                              void* d_out, int out_size, void* d_ws, size_t ws_size,
                              hipStream_t stream) {
    const float* x_in   = (const float*)d_in[0];
    const float* ln_w   = (const float*)d_in[1];
    const float* ln_b   = (const float*)d_in[2];
    const float* in_w   = (const float*)d_in[3];
    const float* conv_w = (const float*)d_in[4];
    const float* conv_b = (const float*)d_in[5];
    const float* xp_w   = (const float*)d_in[6];
    const float* dtp_w  = (const float*)d_in[7];
    const float* dtp_b  = (const float*)d_in[8];
    const float* A_log  = (const float*)d_in[9];
    const float* D_skip = (const float*)d_in[10];
    const float* out_w  = (const float*)d_in[11];
    const float* nf_w   = (const float*)d_in[12];
    const float* nf_b   = (const float*)d_in[13];
    float* out = (float*)d_out;

    float* w = (float*)d_ws;
    float* buf_x = w; w += (size_t)LSEQ * DMODEL;              // residual stream (f32)
    float* dbl   = w; w += (size_t)LSEQ * RPROJ;               // x_proj out (f32)
    float* dtb   = w; w += (size_t)LSEQ * DINNER;              // dt (f32)
    float* Sbuf  = w; w += (size_t)NCHUNK * DSTATE * DINNER;   // chunk summaries
    float* sumdt = w; w += (size_t)NCHUNK * DINNER;
    // bf16 buffers (sized in float units, 2 shorts per float)
    short* h_bf    = (short*)w; w += (size_t)LSEQ * DMODEL / 2;
    short* xz_bf   = (short*)w; w += (size_t)LSEQ * 2 * DINNER / 2;
    short* xc_bf   = (short*)w; w += (size_t)LSEQ * DINNER / 2;
    short* y_bf    = (short*)w; w += (size_t)LSEQ * DINNER / 2;
    short* dbl_bf  = (short*)w; w += (size_t)LSEQ * RPROJ / 2 + 1;
    short* in_w_bf  = (short*)w; w += (size_t)2 * (2 * DINNER) * DMODEL / 2;
    short* xp_w_bf  = (short*)w; w += (size_t)2 * RPROJ * DINNER / 2;
    short* dtp_w_bf = (short*)w; w += (size_t)2 * DINNER * DTRANK / 2;
    short* out_w_bf = (short*)w; w += (size_t)2 * DMODEL * DINNER / 2;

    // weight conversions (all layers at once)
    {
        const int n1 = 2 * (2 * DINNER) * DMODEL;   // 8.4M
        cvt_bf16<<<dim3(n1 / (256 * 8)), dim3(256), 0, stream>>>(in_w, in_w_bf, n1);
        const int n2 = 2 * RPROJ * DINNER;          // 393K
        cvt_bf16<<<dim3(n2 / (256 * 8)), dim3(256), 0, stream>>>(xp_w, xp_w_bf, n2);
        const int n3 = 2 * DMODEL * DINNER;         // 4.2M
        cvt_bf16<<<dim3(n3 / (256 * 8)), dim3(256), 0, stream>>>(out_w, out_w_bf, n3);
        const int n4 = 2 * DINNER * DTRANK;         // 262K
        cvt_bf16<<<dim3(n4 / (256 * 8)), dim3(256), 0, stream>>>(dtp_w, dtp_w_bf, n4);
    }

    for (int layer = 0; layer < 2; layer++) {
        const float* resid_src = (layer == 0) ? x_in : buf_x;
        // 1. LayerNorm -> bf16
        ln_kernel<<<dim3(LSEQ), dim3(256), 0, stream>>>(
            resid_src, ln_w + layer * DMODEL, ln_b + layer * DMODEL,
            nullptr, h_bf);
        // 2. in_proj (MFMA, bf16 out): xz_bf[L,4096] = h * in_w^T
        gemm_mfma<128, 3><<<dim3((2 * DINNER) / 128, LSEQ / 128), dim3(256), 0, stream>>>(
            h_bf, DMODEL, in_w_bf + (size_t)layer * 2 * DINNER * DMODEL, DMODEL,
            nullptr, xz_bf, 2 * DINNER, LSEQ, 2 * DINNER, DMODEL, nullptr, nullptr);
        // 3. conv + silu -> bf16
        conv_silu_kernel<<<dim3((LSEQ * DINNER) / 256), dim3(256), 0, stream>>>(
            xz_bf, conv_w + (size_t)layer * DINNER * DCONV, conv_b + layer * DINNER,
            xc_bf);
        // 4. x_proj (MFMA, dual out): dbl[L,96] f32 + dbl_bf
        gemm_mfma<64, 4><<<dim3((RPROJ + 63) / 64, LSEQ / 128), dim3(256), 0, stream>>>(
            xc_bf, DINNER, xp_w_bf + (size_t)layer * RPROJ * DINNER, DINNER,
            dbl, dbl_bf, RPROJ, LSEQ, RPROJ, DINNER, nullptr, nullptr);
        // 5. dt_proj (MFMA, softplus+bias): dtb[L,2048] f32, K=64
        gemm_mfma<128, 1><<<dim3(DINNER / 128, LSEQ / 128), dim3(256), 0, stream>>>(
            dbl_bf, RPROJ, dtp_w_bf + (size_t)layer * DINNER * DTRANK, DTRANK,
            dtb, nullptr, DINNER, LSEQ, DINNER, DTRANK,
            dtp_b + layer * DINNER, nullptr);
        // 6. chunked selective scan (+ skip + z-gate) -> y_bf
        const float* Al = A_log + (size_t)layer * DINNER * DSTATE;
        scan_pass1<<<dim3(DINNER / 256, NCHUNK), dim3(256), 0, stream>>>(
            dtb, xc_bf, dbl, Al, Sbuf, sumdt);
        scan_pass2<<<dim3((DINNER * DSTATE) / 256), dim3(256), 0, stream>>>(
            Al, sumdt, Sbuf);
        scan_pass3<<<dim3(DINNER / 256, NCHUNK), dim3(256), 0, stream>>>(
            dtb, xc_bf, dbl, xz_bf, Al, D_skip + layer * DINNER, Sbuf, y_bf);
        // 7. out_proj (MFMA) + residual -> buf_x f32
        gemm_mfma<64, 2><<<dim3(DMODEL / 64, LSEQ / 128), dim3(256), 0, stream>>>(
            y_bf, DINNER, out_w_bf + (size_t)layer * DMODEL * DINNER, DINNER,
            buf_x, nullptr, DMODEL, LSEQ, DMODEL, DINNER, nullptr, resid_src);
    }
    // final LayerNorm -> d_out (f32)
    ln_kernel<<<dim3(LSEQ), dim3(256), 0, stream>>>(buf_x, nf_w, nf_b, out, nullptr);
}

// Round 5
// 529.361 us; speedup vs baseline: 1.0846x; 1.0846x over previous
//
#include <hip/hip_runtime.h>
#include <hip/hip_bf16.h>
#include <math.h>

// Problem constants
#define LSEQ 2048
#define DMODEL 1024
#define DINNER 2048
#define DSTATE 16
#define DCONV 4
#define DTRANK 64
#define RPROJ 96   // DTRANK + 2*DSTATE

// Chunked-scan decomposition
#define CHUNK 32
#define NCHUNK (LSEQ / CHUNK)   // 64

#define XSPLIT 4                // split-K factor for x_proj

typedef __attribute__((ext_vector_type(8))) short bf16x8;
typedef __attribute__((ext_vector_type(4))) float f32x4;

__device__ __forceinline__ float softplusf(float x) {
    return (x > 20.f) ? x : log1pf(__expf(x));
}
__device__ __forceinline__ float siluf(float x) {
    return x / (1.f + __expf(-x));
}
// f32 -> bf16 RTNE
__device__ __forceinline__ short f2bf(float f) {
    union { float f; unsigned u; } v; v.f = f;
    unsigned r = v.u + 0x7FFFu + ((v.u >> 16) & 1u);
    return (short)(r >> 16);
}
// bf16 -> f32
__device__ __forceinline__ float bf2f(short h) {
    union { unsigned u; float f; } v;
    v.u = ((unsigned)(unsigned short)h) << 16;
    return v.f;
}

// ---------------- f32 -> bf16 bulk convert (n % 2048 == 0) ----------------
__global__ __launch_bounds__(256) void cvt_bf16(
    const float* __restrict__ s, short* __restrict__ d, int n)
{
    const int i = (blockIdx.x * 256 + threadIdx.x) * 8;
    if (i >= n) return;
    const float4 a = *(const float4*)(s + i);
    const float4 b = *(const float4*)(s + i + 4);
    alignas(16) short h[8];
    h[0] = f2bf(a.x); h[1] = f2bf(a.y); h[2] = f2bf(a.z); h[3] = f2bf(a.w);
    h[4] = f2bf(b.x); h[5] = f2bf(b.y); h[6] = f2bf(b.z); h[7] = f2bf(b.w);
    *(uint4*)(d + i) = *(const uint4*)h;
}

// ---------------- LayerNorm: one block per row; f32 or bf16 out ----------
__global__ __launch_bounds__(256) void ln_kernel(
    const float* __restrict__ x, const float* __restrict__ w,
    const float* __restrict__ b, float* __restrict__ outf,
    short* __restrict__ outb)
{
    __shared__ float s1[256], s2[256];
    const int row = blockIdx.x;
    const int tid = threadIdx.x;
    const float* xr = x + (size_t)row * DMODEL;
    float v[4];
    float s = 0.f, sq = 0.f;
#pragma unroll
    for (int k = 0; k < 4; k++) {
        v[k] = xr[k * 256 + tid];
        s += v[k];
        sq += v[k] * v[k];
    }
    s1[tid] = s; s2[tid] = sq;
    __syncthreads();
    for (int off = 128; off > 0; off >>= 1) {
        if (tid < off) { s1[tid] += s1[tid + off]; s2[tid] += s2[tid + off]; }
        __syncthreads();
    }
    const float mu = s1[0] * (1.f / DMODEL);
    const float var = s2[0] * (1.f / DMODEL) - mu * mu;
    const float rstd = rsqrtf(var + 1e-5f);
#pragma unroll
    for (int k = 0; k < 4; k++) {
        const int i = k * 256 + tid;
        const float o = (v[k] - mu) * rstd * w[i] + b[i];
        if (outf) outf[(size_t)row * DMODEL + i] = o;
        if (outb) outb[(size_t)row * DMODEL + i] = f2bf(o);
    }
}

// ---------------- bf16 MFMA NT GEMM, 64x64 tile ----------------
// C[M,N] = A[M,K] * W[N,K]^T, K per z-slice (blockIdx.z offsets A/W by z*K,
// C by z*csplit). 8KB LDS, ~8 blocks/CU co-resident for latency overlap.
// MODE 0: f32 store            MODE 1: f32 softplus(.+bias[n])
// MODE 2: f32 (. + resid)      MODE 3: bf16 store only
template<int MODE>
__global__ __launch_bounds__(256) void gemm_mfma(
    const short* __restrict__ A, int lda,   // [M,lda] bf16
    const short* __restrict__ W, int ldw,   // [N,ldw] bf16
    float* __restrict__ Cf, short* __restrict__ Cb, int ldc,
    int M, int N, int K,
    const float* __restrict__ bias,
    const float* __restrict__ resid,
    size_t csplit)
{
    __shared__ alignas(16) short As[64 * 32];
    __shared__ alignas(16) short Ws[64 * 32];

    const int tid = threadIdx.x;
    const int lane = tid & 63;
    const int w = tid >> 6;
    const int wr = w >> 1, wc = w & 1;     // 2x2 waves over 64x64
    const int row0 = blockIdx.y * 64;
    const int col0 = blockIdx.x * 64;
    const int kbeg = blockIdx.z * K;

    const int srow = tid >> 2;             // staging row (0..63)
    const int skch = (tid & 3) * 8;        // staging k element offset

    f32x4 acc[2][2];
#pragma unroll
    for (int i = 0; i < 2; i++)
#pragma unroll
        for (int j = 0; j < 2; j++) acc[i][j] = (f32x4)0.f;

    const int lrow = lane & 15;
    const int lk = (lane >> 4) * 8;
    const int wrow = col0 + srow;

    for (int kt = kbeg; kt < kbeg + K; kt += 32) {
        __syncthreads();
        // stage A tile: 64 rows x 32 k (bf16) = 4 KB, one issue
        {
            const short* gp = A + (size_t)(row0 + srow) * lda + kt + skch;
            __builtin_amdgcn_global_load_lds(
                (const __attribute__((address_space(1))) void*)gp,
                (__attribute__((address_space(3))) void*)(As + tid * 8), 16, 0, 0);
        }
        // stage W tile (N guard for x_proj's 96-col case)
        if (wrow < N) {
            const short* gp = W + (size_t)wrow * ldw + kt + skch;
            __builtin_amdgcn_global_load_lds(
                (const __attribute__((address_space(1))) void*)gp,
                (__attribute__((address_space(3))) void*)(Ws + tid * 8), 16, 0, 0);
        }
        __syncthreads();

        bf16x8 af[2], bfr[2];
#pragma unroll
        for (int i = 0; i < 2; i++)
            af[i] = *(const bf16x8*)&As[(wr * 32 + i * 16 + lrow) * 32 + lk];
#pragma unroll
        for (int j = 0; j < 2; j++)
            bfr[j] = *(const bf16x8*)&Ws[(wc * 32 + j * 16 + lrow) * 32 + lk];
#pragma unroll
        for (int i = 0; i < 2; i++)
#pragma unroll
            for (int j = 0; j < 2; j++)
                acc[i][j] = __builtin_amdgcn_mfma_f32_16x16x32_bf16(
                    af[i], bfr[j], acc[i][j], 0, 0, 0);
    }

    if (MODE == 0 && csplit) Cf += blockIdx.z * csplit;

    // epilogue: C/D layout col=lane&15, row=(lane>>4)*4+reg
    const int rbase = row0 + wr * 32;
    const int cbase = col0 + wc * 32;
#pragma unroll
    for (int i = 0; i < 2; i++) {
#pragma unroll
        for (int j = 0; j < 2; j++) {
            const int gcol = cbase + j * 16 + lrow;
            if (gcol < N) {
#pragma unroll
                for (int r = 0; r < 4; r++) {
                    const int grow = rbase + i * 16 + (lane >> 4) * 4 + r;
                    float v = acc[i][j][r];
                    if (MODE == 1) v = softplusf(v + bias[gcol]);
                    if (MODE == 2) v += resid[(size_t)grow * ldc + gcol];
                    if (MODE == 3) {
                        Cb[(size_t)grow * ldc + gcol] = f2bf(v);
                    } else {
                        Cf[(size_t)grow * ldc + gcol] = v;
                    }
                }
            }
        }
    }
}

// ---------------- x_proj split-K combine: dbl = sum of partials ----------
__global__ __launch_bounds__(256) void combine_xproj(
    const float* __restrict__ part,   // [XSPLIT][LSEQ*RPROJ]
    float* __restrict__ dbl, short* __restrict__ dblb)
{
    const int i = (blockIdx.x * 256 + threadIdx.x) * 4;
    const int S = LSEQ * RPROJ;
    float4 v = *(const float4*)(part + i);
#pragma unroll
    for (int s = 1; s < XSPLIT; s++) {
        const float4 p = *(const float4*)(part + s * S + i);
        v.x += p.x; v.y += p.y; v.z += p.z; v.w += p.w;
    }
    *(float4*)(dbl + i) = v;
    alignas(8) short h[4] = {f2bf(v.x), f2bf(v.y), f2bf(v.z), f2bf(v.w)};
    *(unsigned long long*)(dblb + i) = *(const unsigned long long*)h;
}

// ---------------- Causal depthwise conv (k=4) + bias + silu --------------
// 8 channels per thread, bf16x8 vector loads/stores.
__global__ __launch_bounds__(256) void conv_silu_kernel(
    const short* __restrict__ xzb, const float* __restrict__ cw,
    const float* __restrict__ cb, short* __restrict__ xcb)
{
    const int g = blockIdx.x * 256 + threadIdx.x;   // over L * DINNER/8
    const int t = g >> 8;             // DINNER/8 = 256 groups per t
    const int c0 = (g & 255) * 8;
    float acc[8];
#pragma unroll
    for (int j = 0; j < 8; j++) acc[j] = cb[c0 + j];
#pragma unroll
    for (int k = 0; k < DCONV; k++) {
        const int tt = t - (DCONV - 1) + k;
        if (tt >= 0) {
            const bf16x8 v = *(const bf16x8*)(xzb + (size_t)tt * (2 * DINNER) + c0);
#pragma unroll
            for (int j = 0; j < 8; j++)
                acc[j] += bf2f(v[j]) * cw[(c0 + j) * DCONV + k];
        }
    }
    alignas(16) short h[8];
#pragma unroll
    for (int j = 0; j < 8; j++) h[j] = f2bf(siluf(acc[j]));
    *(uint4*)(xcb + (size_t)t * DINNER + c0) = *(const uint4*)h;
}

// ============ Chunked selective scan ============
__global__ __launch_bounds__(256) void scan_pass1(
    const float* __restrict__ dt,    // [L, DINNER] f32
    const short* __restrict__ xcb,   // [L, DINNER] bf16
    const float* __restrict__ dbl,   // [L, RPROJ] f32
    const float* __restrict__ A_log,
    float* __restrict__ S,           // [NCHUNK][DSTATE][DINNER]
    float* __restrict__ sumdt)       // [NCHUNK][DINNER]
{
    const int e = blockIdx.x * 256 + threadIdx.x;
    const int c = blockIdx.y;
    float a[DSTATE];
#pragma unroll
    for (int n = 0; n < DSTATE; n++) a[n] = -__expf(A_log[(size_t)e * DSTATE + n]);
    float h[DSTATE];
#pragma unroll
    for (int n = 0; n < DSTATE; n++) h[n] = 0.f;
    float sd = 0.f;

    __shared__ float sBC[CHUNK][32];
    for (int i = threadIdx.x; i < CHUNK * 32; i += 256) {
        const int tl = i >> 5, j = i & 31;
        sBC[tl][j] = dbl[(size_t)(c * CHUNK + tl) * RPROJ + DTRANK + j];
    }
    __syncthreads();

    for (int tl = 0; tl < CHUNK; tl++) {
        const int t = c * CHUNK + tl;
        const float dtv = dt[(size_t)t * DINNER + e];
        const float du = dtv * bf2f(xcb[(size_t)t * DINNER + e]);
        sd += dtv;
#pragma unroll
        for (int n = 0; n < DSTATE; n++) {
            const float dA = __expf(dtv * a[n]);
            h[n] = dA * h[n] + du * sBC[tl][n];
        }
    }
    sumdt[(size_t)c * DINNER + e] = sd;
#pragma unroll
    for (int n = 0; n < DSTATE; n++)
        S[((size_t)c * DSTATE + n) * DINNER + e] = h[n];
}

__global__ __launch_bounds__(256) void scan_pass2(
    const float* __restrict__ A_log,
    const float* __restrict__ sumdt,
    float* __restrict__ S)
{
    const int idx = blockIdx.x * 256 + threadIdx.x;
    const int e = idx & (DINNER - 1);
    const int n = idx >> 11;
    const float a = -__expf(A_log[(size_t)e * DSTATE + n]);
    float H = 0.f;
    for (int c = 0; c < NCHUNK; c++) {
        const size_t off = ((size_t)c * DSTATE + n) * DINNER + e;
        const float tmp = S[off];
        S[off] = H;
        const float P = __expf(a * sumdt[(size_t)c * DINNER + e]);
        H = P * H + tmp;
    }
}

// pass3: seeded chunk-local scan -> gated y (bf16 for out_proj)
__global__ __launch_bounds__(256) void scan_pass3(
    const float* __restrict__ dt,
    const short* __restrict__ xcb,
    const float* __restrict__ dbl,
    const short* __restrict__ xzb,   // z at cols DINNER.. (bf16)
    const float* __restrict__ A_log,
    const float* __restrict__ Dp,
    const float* __restrict__ S,
    short* __restrict__ yb)
{
    const int e = blockIdx.x * 256 + threadIdx.x;
    const int c = blockIdx.y;
    float a[DSTATE];
#pragma unroll
    for (int n = 0; n < DSTATE; n++) a[n] = -__expf(A_log[(size_t)e * DSTATE + n]);
    float h[DSTATE];
#pragma unroll
    for (int n = 0; n < DSTATE; n++)
        h[n] = S[((size_t)c * DSTATE + n) * DINNER + e];
    const float dskip = Dp[e];

    __shared__ float sBC[CHUNK][32];
    for (int i = threadIdx.x; i < CHUNK * 32; i += 256) {
        const int tl = i >> 5, j = i & 31;
        sBC[tl][j] = dbl[(size_t)(c * CHUNK + tl) * RPROJ + DTRANK + j];
    }
    __syncthreads();

    for (int tl = 0; tl < CHUNK; tl++) {
        const int t = c * CHUNK + tl;
        const float dtv = dt[(size_t)t * DINNER + e];
        const float xcv = bf2f(xcb[(size_t)t * DINNER + e]);
        const float du = dtv * xcv;
        float yv = 0.f;
#pragma unroll
        for (int n = 0; n < DSTATE; n++) {
            const float dA = __expf(dtv * a[n]);
            h[n] = dA * h[n] + du * sBC[tl][n];
            yv += h[n] * sBC[tl][16 + n];
        }
        const float zv = bf2f(xzb[(size_t)t * (2 * DINNER) + DINNER + e]);
        yv = (yv + xcv * dskip) * siluf(zv);
        yb[(size_t)t * DINNER + e] = f2bf(yv);
    }
}

extern "C" void kernel_launch(void* const* d_in, const int* in_sizes, int n_in,
                              void* d_out, int out_size, void* d_ws, size_t ws_size,
                              hipStream_t stream) {
    const float* x_in   = (const float*)d_in[0];
    const float* ln_w   = (const float*)d_in[1];
    const float* ln_b   = (const float*)d_in[2];
    const float* in_w   = (const float*)d_in[3];
    const float* conv_w = (const float*)d_in[4];
    const float* conv_b = (const float*)d_in[5];
    const float* xp_w   = (const float*)d_in[6];
    const float* dtp_w  = (const float*)d_in[7];
    const float* dtp_b  = (const float*)d_in[8];
    const float* A_log  = (const float*)d_in[9];
    const float* D_skip = (const float*)d_in[10];
    const float* out_w  = (const float*)d_in[11];
    const float* nf_w   = (const float*)d_in[12];
    const float* nf_b   = (const float*)d_in[13];
    float* out = (float*)d_out;

    float* w = (float*)d_ws;
    float* buf_x = w; w += (size_t)LSEQ * DMODEL;              // residual stream (f32)
    float* dbl   = w; w += (size_t)LSEQ * RPROJ;               // x_proj out (f32)
    float* xpart = w; w += (size_t)XSPLIT * LSEQ * RPROJ;      // x_proj split-K partials
    float* dtb   = w; w += (size_t)LSEQ * DINNER;              // dt (f32)
    float* Sbuf  = w; w += (size_t)NCHUNK * DSTATE * DINNER;   // chunk summaries
    float* sumdt = w; w += (size_t)NCHUNK * DINNER;
    // bf16 buffers (sized in float units, 2 shorts per float)
    short* h_bf    = (short*)w; w += (size_t)LSEQ * DMODEL / 2;
    short* xz_bf   = (short*)w; w += (size_t)LSEQ * 2 * DINNER / 2;
    short* xc_bf   = (short*)w; w += (size_t)LSEQ * DINNER / 2;
    short* y_bf    = (short*)w; w += (size_t)LSEQ * DINNER / 2;
    short* dbl_bf  = (short*)w; w += (size_t)LSEQ * RPROJ / 2 + 1;
    short* in_w_bf  = (short*)w; w += (size_t)2 * (2 * DINNER) * DMODEL / 2;
    short* xp_w_bf  = (short*)w; w += (size_t)2 * RPROJ * DINNER / 2;
    short* dtp_w_bf = (short*)w; w += (size_t)2 * DINNER * DTRANK / 2;
    short* out_w_bf = (short*)w; w += (size_t)2 * DMODEL * DINNER / 2;

    // weight conversions (all layers at once)
    {
        const int n1 = 2 * (2 * DINNER) * DMODEL;   // 8.4M
        cvt_bf16<<<dim3(n1 / (256 * 8)), dim3(256), 0, stream>>>(in_w, in_w_bf, n1);
        const int n2 = 2 * RPROJ * DINNER;          // 393K
        cvt_bf16<<<dim3(n2 / (256 * 8)), dim3(256), 0, stream>>>(xp_w, xp_w_bf, n2);
        const int n3 = 2 * DMODEL * DINNER;         // 4.2M
        cvt_bf16<<<dim3(n3 / (256 * 8)), dim3(256), 0, stream>>>(out_w, out_w_bf, n3);
        const int n4 = 2 * DINNER * DTRANK;         // 262K
        cvt_bf16<<<dim3(n4 / (256 * 8)), dim3(256), 0, stream>>>(dtp_w, dtp_w_bf, n4);
    }

    for (int layer = 0; layer < 2; layer++) {
        const float* resid_src = (layer == 0) ? x_in : buf_x;
        // 1. LayerNorm -> bf16
        ln_kernel<<<dim3(LSEQ), dim3(256), 0, stream>>>(
            resid_src, ln_w + layer * DMODEL, ln_b + layer * DMODEL,
            nullptr, h_bf);
        // 2. in_proj (MFMA, bf16 out): xz_bf[L,4096] = h * in_w^T  (2048 blocks)
        gemm_mfma<3><<<dim3((2 * DINNER) / 64, LSEQ / 64), dim3(256), 0, stream>>>(
            h_bf, DMODEL, in_w_bf + (size_t)layer * 2 * DINNER * DMODEL, DMODEL,
            nullptr, xz_bf, 2 * DINNER, LSEQ, 2 * DINNER, DMODEL, nullptr, nullptr, 0);
        // 3. conv + silu -> bf16 (vectorized)
        conv_silu_kernel<<<dim3((LSEQ * DINNER / 8) / 256), dim3(256), 0, stream>>>(
            xz_bf, conv_w + (size_t)layer * DINNER * DCONV, conv_b + layer * DINNER,
            xc_bf);
        // 4. x_proj (MFMA, split-K=4 -> partials) + combine (f32 + bf16 out)
        gemm_mfma<0><<<dim3(2, LSEQ / 64, XSPLIT), dim3(256), 0, stream>>>(
            xc_bf, DINNER, xp_w_bf + (size_t)layer * RPROJ * DINNER, DINNER,
            xpart, nullptr, RPROJ, LSEQ, RPROJ, DINNER / XSPLIT, nullptr, nullptr,
            (size_t)LSEQ * RPROJ);
        combine_xproj<<<dim3((LSEQ * RPROJ / 4) / 256), dim3(256), 0, stream>>>(
            xpart, dbl, dbl_bf);
        // 5. dt_proj (MFMA, softplus+bias): dtb[L,2048] f32, K=64  (1024 blocks)
        gemm_mfma<1><<<dim3(DINNER / 64, LSEQ / 64), dim3(256), 0, stream>>>(
            dbl_bf, RPROJ, dtp_w_bf + (size_t)layer * DINNER * DTRANK, DTRANK,
            dtb, nullptr, DINNER, LSEQ, DINNER, DTRANK,
            dtp_b + layer * DINNER, nullptr, 0);
        // 6. chunked selective scan (+ skip + z-gate) -> y_bf
        const float* Al = A_log + (size_t)layer * DINNER * DSTATE;
        scan_pass1<<<dim3(DINNER / 256, NCHUNK), dim3(256), 0, stream>>>(
            dtb, xc_bf, dbl, Al, Sbuf, sumdt);
        scan_pass2<<<dim3((DINNER * DSTATE) / 256), dim3(256), 0, stream>>>(
            Al, sumdt, Sbuf);
        scan_pass3<<<dim3(DINNER / 256, NCHUNK), dim3(256), 0, stream>>>(
            dtb, xc_bf, dbl, xz_bf, Al, D_skip + layer * DINNER, Sbuf, y_bf);
        // 7. out_proj (MFMA) + residual -> buf_x f32  (512 blocks)
        gemm_mfma<2><<<dim3(DMODEL / 64, LSEQ / 64), dim3(256), 0, stream>>>(
            y_bf, DINNER, out_w_bf + (size_t)layer * DMODEL * DINNER, DINNER,
            buf_x, nullptr, DMODEL, LSEQ, DMODEL, DINNER, nullptr, resid_src, 0);
    }
    // final LayerNorm -> d_out (f32)
    ln_kernel<<<dim3(LSEQ), dim3(256), 0, stream>>>(buf_x, nf_w, nf_b, out, nullptr);
}

// Round 6
// 517.054 us; speedup vs baseline: 1.1104x; 1.0238x over previous
//
#include <hip/hip_runtime.h>
#include <hip/hip_bf16.h>
#include <math.h>

// Problem constants
#define LSEQ 2048
#define DMODEL 1024
#define DINNER 2048
#define DSTATE 16
#define DCONV 4
#define DTRANK 64
#define RPROJ 96   // DTRANK + 2*DSTATE

// Chunked-scan decomposition
#define CHUNK 32
#define NCHUNK (LSEQ / CHUNK)   // 64

#define XSPLIT 4                // split-K factor for x_proj

typedef __attribute__((ext_vector_type(8))) short bf16x8;
typedef __attribute__((ext_vector_type(4))) float f32x4;

__device__ __forceinline__ float softplusf(float x) {
    return (x > 20.f) ? x : log1pf(__expf(x));
}
__device__ __forceinline__ float siluf(float x) {
    return x / (1.f + __expf(-x));
}
// f32 -> bf16 RTNE
__device__ __forceinline__ short f2bf(float f) {
    union { float f; unsigned u; } v; v.f = f;
    unsigned r = v.u + 0x7FFFu + ((v.u >> 16) & 1u);
    return (short)(r >> 16);
}
// bf16 -> f32
__device__ __forceinline__ float bf2f(short h) {
    union { unsigned u; float f; } v;
    v.u = ((unsigned)(unsigned short)h) << 16;
    return v.f;
}

__device__ __forceinline__ void cvt8(const float* __restrict__ s,
                                     short* __restrict__ d, int i) {
    const float4 a = *(const float4*)(s + i);
    const float4 b = *(const float4*)(s + i + 4);
    alignas(16) short h[8];
    h[0] = f2bf(a.x); h[1] = f2bf(a.y); h[2] = f2bf(a.z); h[3] = f2bf(a.w);
    h[4] = f2bf(b.x); h[5] = f2bf(b.y); h[6] = f2bf(b.z); h[7] = f2bf(b.w);
    *(uint4*)(d + i) = *(const uint4*)h;
}

// ---------------- fused f32 -> bf16 convert of all 4 weight tensors -------
__global__ __launch_bounds__(256) void cvt_weights(
    const float* __restrict__ s0, short* __restrict__ d0, int n0,
    const float* __restrict__ s1, short* __restrict__ d1, int n1,
    const float* __restrict__ s2, short* __restrict__ d2, int n2,
    const float* __restrict__ s3, short* __restrict__ d3, int n3)
{
    int i = (blockIdx.x * 256 + threadIdx.x) * 8;
    if (i < n0) { cvt8(s0, d0, i); return; }
    i -= n0;
    if (i < n1) { cvt8(s1, d1, i); return; }
    i -= n1;
    if (i < n2) { cvt8(s2, d2, i); return; }
    i -= n2;
    if (i < n3) { cvt8(s3, d3, i); return; }
}

// ---------------- LayerNorm: one block per row; f32 or bf16 out ----------
__global__ __launch_bounds__(256) void ln_kernel(
    const float* __restrict__ x, const float* __restrict__ w,
    const float* __restrict__ b, float* __restrict__ outf,
    short* __restrict__ outb)
{
    __shared__ float s1[256], s2[256];
    const int row = blockIdx.x;
    const int tid = threadIdx.x;
    const float* xr = x + (size_t)row * DMODEL;
    float v[4];
    float s = 0.f, sq = 0.f;
#pragma unroll
    for (int k = 0; k < 4; k++) {
        v[k] = xr[k * 256 + tid];
        s += v[k];
        sq += v[k] * v[k];
    }
    s1[tid] = s; s2[tid] = sq;
    __syncthreads();
    for (int off = 128; off > 0; off >>= 1) {
        if (tid < off) { s1[tid] += s1[tid + off]; s2[tid] += s2[tid + off]; }
        __syncthreads();
    }
    const float mu = s1[0] * (1.f / DMODEL);
    const float var = s2[0] * (1.f / DMODEL) - mu * mu;
    const float rstd = rsqrtf(var + 1e-5f);
#pragma unroll
    for (int k = 0; k < 4; k++) {
        const int i = k * 256 + tid;
        const float o = (v[k] - mu) * rstd * w[i] + b[i];
        if (outf) outf[(size_t)row * DMODEL + i] = o;
        if (outb) outb[(size_t)row * DMODEL + i] = f2bf(o);
    }
}

// ---------------- bf16 MFMA NT GEMM, 64x64 tile, XOR-swizzled LDS --------
// C[M,N] = A[M,K] * W[N,K]^T, K per z-slice (blockIdx.z offsets A/W by z*K,
// C by z*csplit). 8KB LDS, many blocks/CU for latency overlap.
// LDS layout: row r (64B = 4 chunks of 16B); logical chunk c stored at
// physical chunk p = c ^ ((r>>1)&3). Staging slot tid holds (r=tid>>2,
// p=tid&3) -> loads global chunk (tid&3)^((r>>1)&3). This makes the
// 16-lane quarter-wave ds_read_b128 pattern 2-way (free) instead of 8-way.
// MODE 0: f32 store            MODE 1: f32 softplus(.+bias[n])
// MODE 2: f32 (. + resid)      MODE 3: bf16 store only
template<int MODE>
__global__ __launch_bounds__(256) void gemm_mfma(
    const short* __restrict__ A, int lda,   // [M,lda] bf16
    const short* __restrict__ W, int ldw,   // [N,ldw] bf16
    float* __restrict__ Cf, short* __restrict__ Cb, int ldc,
    int M, int N, int K,
    const float* __restrict__ bias,
    const float* __restrict__ resid,
    size_t csplit)
{
    __shared__ alignas(16) short As[64 * 32];
    __shared__ alignas(16) short Ws[64 * 32];

    const int tid = threadIdx.x;
    const int lane = tid & 63;
    const int w = tid >> 6;
    const int wr = w >> 1, wc = w & 1;     // 2x2 waves over 64x64
    const int row0 = blockIdx.y * 64;
    const int col0 = blockIdx.x * 64;
    const int kbeg = blockIdx.z * K;

    const int srow = tid >> 2;                              // staging row (0..63)
    const int skch = ((tid & 3) ^ ((srow >> 1) & 3)) * 8;   // swizzled k chunk

    f32x4 acc[2][2];
#pragma unroll
    for (int i = 0; i < 2; i++)
#pragma unroll
        for (int j = 0; j < 2; j++) acc[i][j] = (f32x4)0.f;

    const int lrow = lane & 15;
    const int q = lane >> 4;               // logical chunk wanted by this lane
    const int wrow = col0 + srow;

    for (int kt = kbeg; kt < kbeg + K; kt += 32) {
        __syncthreads();
        // stage A tile: 64 rows x 32 k (bf16) = 4 KB, one issue
        {
            const short* gp = A + (size_t)(row0 + srow) * lda + kt + skch;
            __builtin_amdgcn_global_load_lds(
                (const __attribute__((address_space(1))) void*)gp,
                (__attribute__((address_space(3))) void*)(As + tid * 8), 16, 0, 0);
        }
        // stage W tile (N guard for x_proj's 96-col case)
        if (wrow < N) {
            const short* gp = W + (size_t)wrow * ldw + kt + skch;
            __builtin_amdgcn_global_load_lds(
                (const __attribute__((address_space(1))) void*)gp,
                (__attribute__((address_space(3))) void*)(Ws + tid * 8), 16, 0, 0);
        }
        __syncthreads();

        bf16x8 af[2], bfr[2];
#pragma unroll
        for (int i = 0; i < 2; i++) {
            const int R = wr * 32 + i * 16 + lrow;
            af[i] = *(const bf16x8*)&As[R * 32 + ((q ^ ((R >> 1) & 3)) * 8)];
        }
#pragma unroll
        for (int j = 0; j < 2; j++) {
            const int R = wc * 32 + j * 16 + lrow;
            bfr[j] = *(const bf16x8*)&Ws[R * 32 + ((q ^ ((R >> 1) & 3)) * 8)];
        }
#pragma unroll
        for (int i = 0; i < 2; i++)
#pragma unroll
            for (int j = 0; j < 2; j++)
                acc[i][j] = __builtin_amdgcn_mfma_f32_16x16x32_bf16(
                    af[i], bfr[j], acc[i][j], 0, 0, 0);
    }

    if (MODE == 0 && csplit) Cf += blockIdx.z * csplit;

    // epilogue: C/D layout col=lane&15, row=(lane>>4)*4+reg
    const int rbase = row0 + wr * 32;
    const int cbase = col0 + wc * 32;
#pragma unroll
    for (int i = 0; i < 2; i++) {
#pragma unroll
        for (int j = 0; j < 2; j++) {
            const int gcol = cbase + j * 16 + lrow;
            if (gcol < N) {
#pragma unroll
                for (int r = 0; r < 4; r++) {
                    const int grow = rbase + i * 16 + (lane >> 4) * 4 + r;
                    float v = acc[i][j][r];
                    if (MODE == 1) v = softplusf(v + bias[gcol]);
                    if (MODE == 2) v += resid[(size_t)grow * ldc + gcol];
                    if (MODE == 3) {
                        Cb[(size_t)grow * ldc + gcol] = f2bf(v);
                    } else {
                        Cf[(size_t)grow * ldc + gcol] = v;
                    }
                }
            }
        }
    }
}

// ---------------- x_proj split-K combine: dbl = sum of partials ----------
__global__ __launch_bounds__(256) void combine_xproj(
    const float* __restrict__ part,   // [XSPLIT][LSEQ*RPROJ]
    float* __restrict__ dbl, short* __restrict__ dblb)
{
    const int i = (blockIdx.x * 256 + threadIdx.x) * 4;
    const int S = LSEQ * RPROJ;
    float4 v = *(const float4*)(part + i);
#pragma unroll
    for (int s = 1; s < XSPLIT; s++) {
        const float4 p = *(const float4*)(part + s * S + i);
        v.x += p.x; v.y += p.y; v.z += p.z; v.w += p.w;
    }
    *(float4*)(dbl + i) = v;
    alignas(8) short h[4] = {f2bf(v.x), f2bf(v.y), f2bf(v.z), f2bf(v.w)};
    *(unsigned long long*)(dblb + i) = *(const unsigned long long*)h;
}

// ---------------- Causal depthwise conv (k=4) + bias + silu --------------
// 8 channels per thread, bf16x8 vector loads/stores.
__global__ __launch_bounds__(256) void conv_silu_kernel(
    const short* __restrict__ xzb, const float* __restrict__ cw,
    const float* __restrict__ cb, short* __restrict__ xcb)
{
    const int g = blockIdx.x * 256 + threadIdx.x;   // over L * DINNER/8
    const int t = g >> 8;             // DINNER/8 = 256 groups per t
    const int c0 = (g & 255) * 8;
    float acc[8];
#pragma unroll
    for (int j = 0; j < 8; j++) acc[j] = cb[c0 + j];
#pragma unroll
    for (int k = 0; k < DCONV; k++) {
        const int tt = t - (DCONV - 1) + k;
        if (tt >= 0) {
            const bf16x8 v = *(const bf16x8*)(xzb + (size_t)tt * (2 * DINNER) + c0);
#pragma unroll
            for (int j = 0; j < 8; j++)
                acc[j] += bf2f(v[j]) * cw[(c0 + j) * DCONV + k];
        }
    }
    alignas(16) short h[8];
#pragma unroll
    for (int j = 0; j < 8; j++) h[j] = f2bf(siluf(acc[j]));
    *(uint4*)(xcb + (size_t)t * DINNER + c0) = *(const uint4*)h;
}

// ============ Chunked selective scan ============
__global__ __launch_bounds__(256) void scan_pass1(
    const float* __restrict__ dt,    // [L, DINNER] f32
    const short* __restrict__ xcb,   // [L, DINNER] bf16
    const float* __restrict__ dbl,   // [L, RPROJ] f32
    const float* __restrict__ A_log,
    float* __restrict__ S,           // [NCHUNK][DSTATE][DINNER]
    float* __restrict__ sumdt)       // [NCHUNK][DINNER]
{
    const int e = blockIdx.x * 256 + threadIdx.x;
    const int c = blockIdx.y;
    float a[DSTATE];
#pragma unroll
    for (int n = 0; n < DSTATE; n++) a[n] = -__expf(A_log[(size_t)e * DSTATE + n]);
    float h[DSTATE];
#pragma unroll
    for (int n = 0; n < DSTATE; n++) h[n] = 0.f;
    float sd = 0.f;

    __shared__ float sBC[CHUNK][32];
    for (int i = threadIdx.x; i < CHUNK * 32; i += 256) {
        const int tl = i >> 5, j = i & 31;
        sBC[tl][j] = dbl[(size_t)(c * CHUNK + tl) * RPROJ + DTRANK + j];
    }
    __syncthreads();

    for (int tl = 0; tl < CHUNK; tl++) {
        const int t = c * CHUNK + tl;
        const float dtv = dt[(size_t)t * DINNER + e];
        const float du = dtv * bf2f(xcb[(size_t)t * DINNER + e]);
        sd += dtv;
#pragma unroll
        for (int n = 0; n < DSTATE; n++) {
            const float dA = __expf(dtv * a[n]);
            h[n] = dA * h[n] + du * sBC[tl][n];
        }
    }
    sumdt[(size_t)c * DINNER + e] = sd;
#pragma unroll
    for (int n = 0; n < DSTATE; n++)
        S[((size_t)c * DSTATE + n) * DINNER + e] = h[n];
}

__global__ __launch_bounds__(256) void scan_pass2(
    const float* __restrict__ A_log,
    const float* __restrict__ sumdt,
    float* __restrict__ S)
{
    const int idx = blockIdx.x * 256 + threadIdx.x;
    const int e = idx & (DINNER - 1);
    const int n = idx >> 11;
    const float a = -__expf(A_log[(size_t)e * DSTATE + n]);
    float H = 0.f;
    for (int c = 0; c < NCHUNK; c++) {
        const size_t off = ((size_t)c * DSTATE + n) * DINNER + e;
        const float tmp = S[off];
        S[off] = H;
        const float P = __expf(a * sumdt[(size_t)c * DINNER + e]);
        H = P * H + tmp;
    }
}

// pass3: seeded chunk-local scan -> gated y (bf16 for out_proj)
__global__ __launch_bounds__(256) void scan_pass3(
    const float* __restrict__ dt,
    const short* __restrict__ xcb,
    const float* __restrict__ dbl,
    const short* __restrict__ xzb,   // z at cols DINNER.. (bf16)
    const float* __restrict__ A_log,
    const float* __restrict__ Dp,
    const float* __restrict__ S,
    short* __restrict__ yb)
{
    const int e = blockIdx.x * 256 + threadIdx.x;
    const int c = blockIdx.y;
    float a[DSTATE];
#pragma unroll
    for (int n = 0; n < DSTATE; n++) a[n] = -__expf(A_log[(size_t)e * DSTATE + n]);
    float h[DSTATE];
#pragma unroll
    for (int n = 0; n < DSTATE; n++)
        h[n] = S[((size_t)c * DSTATE + n) * DINNER + e];
    const float dskip = Dp[e];

    __shared__ float sBC[CHUNK][32];
    for (int i = threadIdx.x; i < CHUNK * 32; i += 256) {
        const int tl = i >> 5, j = i & 31;
        sBC[tl][j] = dbl[(size_t)(c * CHUNK + tl) * RPROJ + DTRANK + j];
    }
    __syncthreads();

    for (int tl = 0; tl < CHUNK; tl++) {
        const int t = c * CHUNK + tl;
        const float dtv = dt[(size_t)t * DINNER + e];
        const float xcv = bf2f(xcb[(size_t)t * DINNER + e]);
        const float du = dtv * xcv;
        float yv = 0.f;
#pragma unroll
        for (int n = 0; n < DSTATE; n++) {
            const float dA = __expf(dtv * a[n]);
            h[n] = dA * h[n] + du * sBC[tl][n];
            yv += h[n] * sBC[tl][16 + n];
        }
        const float zv = bf2f(xzb[(size_t)t * (2 * DINNER) + DINNER + e]);
        yv = (yv + xcv * dskip) * siluf(zv);
        yb[(size_t)t * DINNER + e] = f2bf(yv);
    }
}

extern "C" void kernel_launch(void* const* d_in, const int* in_sizes, int n_in,
                              void* d_out, int out_size, void* d_ws, size_t ws_size,
                              hipStream_t stream) {
    const float* x_in   = (const float*)d_in[0];
    const float* ln_w   = (const float*)d_in[1];
    const float* ln_b   = (const float*)d_in[2];
    const float* in_w   = (const float*)d_in[3];
    const float* conv_w = (const float*)d_in[4];
    const float* conv_b = (const float*)d_in[5];
    const float* xp_w   = (const float*)d_in[6];
    const float* dtp_w  = (const float*)d_in[7];
    const float* dtp_b  = (const float*)d_in[8];
    const float* A_log  = (const float*)d_in[9];
    const float* D_skip = (const float*)d_in[10];
    const float* out_w  = (const float*)d_in[11];
    const float* nf_w   = (const float*)d_in[12];
    const float* nf_b   = (const float*)d_in[13];
    float* out = (float*)d_out;

    float* w = (float*)d_ws;
    float* buf_x = w; w += (size_t)LSEQ * DMODEL;              // residual stream (f32)
    float* dbl   = w; w += (size_t)LSEQ * RPROJ;               // x_proj out (f32)
    float* xpart = w; w += (size_t)XSPLIT * LSEQ * RPROJ;      // x_proj split-K partials
    float* dtb   = w; w += (size_t)LSEQ * DINNER;              // dt (f32)
    float* Sbuf  = w; w += (size_t)NCHUNK * DSTATE * DINNER;   // chunk summaries
    float* sumdt = w; w += (size_t)NCHUNK * DINNER;
    // bf16 buffers (sized in float units, 2 shorts per float)
    short* h_bf    = (short*)w; w += (size_t)LSEQ * DMODEL / 2;
    short* xz_bf   = (short*)w; w += (size_t)LSEQ * 2 * DINNER / 2;
    short* xc_bf   = (short*)w; w += (size_t)LSEQ * DINNER / 2;
    short* y_bf    = (short*)w; w += (size_t)LSEQ * DINNER / 2;
    short* dbl_bf  = (short*)w; w += (size_t)LSEQ * RPROJ / 2 + 1;
    short* in_w_bf  = (short*)w; w += (size_t)2 * (2 * DINNER) * DMODEL / 2;
    short* xp_w_bf  = (short*)w; w += (size_t)2 * RPROJ * DINNER / 2;
    short* dtp_w_bf = (short*)w; w += (size_t)2 * DINNER * DTRANK / 2;
    short* out_w_bf = (short*)w; w += (size_t)2 * DMODEL * DINNER / 2;

    // fused weight conversion (all layers, all 4 tensors, one dispatch)
    {
        const int n1 = 2 * (2 * DINNER) * DMODEL;   // 8388608
        const int n2 = 2 * RPROJ * DINNER;          // 393216
        const int n3 = 2 * DMODEL * DINNER;         // 4194304
        const int n4 = 2 * DINNER * DTRANK;         // 262144
        const int total = n1 + n2 + n3 + n4;        // 13238272
        cvt_weights<<<dim3(total / (256 * 8)), dim3(256), 0, stream>>>(
            in_w, in_w_bf, n1, xp_w, xp_w_bf, n2,
            out_w, out_w_bf, n3, dtp_w, dtp_w_bf, n4);
    }

    for (int layer = 0; layer < 2; layer++) {
        const float* resid_src = (layer == 0) ? x_in : buf_x;
        // 1. LayerNorm -> bf16
        ln_kernel<<<dim3(LSEQ), dim3(256), 0, stream>>>(
            resid_src, ln_w + layer * DMODEL, ln_b + layer * DMODEL,
            nullptr, h_bf);
        // 2. in_proj (MFMA, bf16 out): xz_bf[L,4096] = h * in_w^T  (2048 blocks)
        gemm_mfma<3><<<dim3((2 * DINNER) / 64, LSEQ / 64), dim3(256), 0, stream>>>(
            h_bf, DMODEL, in_w_bf + (size_t)layer * 2 * DINNER * DMODEL, DMODEL,
            nullptr, xz_bf, 2 * DINNER, LSEQ, 2 * DINNER, DMODEL, nullptr, nullptr, 0);
        // 3. conv + silu -> bf16 (vectorized)
        conv_silu_kernel<<<dim3((LSEQ * DINNER / 8) / 256), dim3(256), 0, stream>>>(
            xz_bf, conv_w + (size_t)layer * DINNER * DCONV, conv_b + layer * DINNER,
            xc_bf);
        // 4. x_proj (MFMA, split-K=4 -> partials) + combine (f32 + bf16 out)
        gemm_mfma<0><<<dim3(2, LSEQ / 64, XSPLIT), dim3(256), 0, stream>>>(
            xc_bf, DINNER, xp_w_bf + (size_t)layer * RPROJ * DINNER, DINNER,
            xpart, nullptr, RPROJ, LSEQ, RPROJ, DINNER / XSPLIT, nullptr, nullptr,
            (size_t)LSEQ * RPROJ);
        combine_xproj<<<dim3((LSEQ * RPROJ / 4) / 256), dim3(256), 0, stream>>>(
            xpart, dbl, dbl_bf);
        // 5. dt_proj (MFMA, softplus+bias): dtb[L,2048] f32, K=64  (1024 blocks)
        gemm_mfma<1><<<dim3(DINNER / 64, LSEQ / 64), dim3(256), 0, stream>>>(
            dbl_bf, RPROJ, dtp_w_bf + (size_t)layer * DINNER * DTRANK, DTRANK,
            dtb, nullptr, DINNER, LSEQ, DINNER, DTRANK,
            dtp_b + layer * DINNER, nullptr, 0);
        // 6. chunked selective scan (+ skip + z-gate) -> y_bf
        const float* Al = A_log + (size_t)layer * DINNER * DSTATE;
        scan_pass1<<<dim3(DINNER / 256, NCHUNK), dim3(256), 0, stream>>>(
            dtb, xc_bf, dbl, Al, Sbuf, sumdt);
        scan_pass2<<<dim3((DINNER * DSTATE) / 256), dim3(256), 0, stream>>>(
            Al, sumdt, Sbuf);
        scan_pass3<<<dim3(DINNER / 256, NCHUNK), dim3(256), 0, stream>>>(
            dtb, xc_bf, dbl, xz_bf, Al, D_skip + layer * DINNER, Sbuf, y_bf);
        // 7. out_proj (MFMA) + residual -> buf_x f32  (512 blocks)
        gemm_mfma<2><<<dim3(DMODEL / 64, LSEQ / 64), dim3(256), 0, stream>>>(
            y_bf, DINNER, out_w_bf + (size_t)layer * DMODEL * DINNER, DINNER,
            buf_x, nullptr, DMODEL, LSEQ, DMODEL, DINNER, nullptr, resid_src, 0);
    }
    // final LayerNorm -> d_out (f32)
    ln_kernel<<<dim3(LSEQ), dim3(256), 0, stream>>>(buf_x, nf_w, nf_b, out, nullptr);
}

// Round 7
// 491.091 us; speedup vs baseline: 1.1691x; 1.0529x over previous
//
#include <hip/hip_runtime.h>
#include <hip/hip_bf16.h>
#include <math.h>

// Problem constants
#define LSEQ 2048
#define DMODEL 1024
#define DINNER 2048
#define DSTATE 16
#define DCONV 4
#define DTRANK 64
#define RPROJ 96   // DTRANK + 2*DSTATE

// Chunked-scan decomposition
#define CHUNK 16
#define NCHUNK (LSEQ / CHUNK)   // 128

#define XSPLIT 4                // split-K factor for x_proj

typedef __attribute__((ext_vector_type(8))) short bf16x8;
typedef __attribute__((ext_vector_type(4))) float f32x4;

__device__ __forceinline__ float softplusf(float x) {
    return (x > 20.f) ? x : log1pf(__expf(x));
}
__device__ __forceinline__ float siluf(float x) {
    return x / (1.f + __expf(-x));
}
// f32 -> bf16 RTNE
__device__ __forceinline__ short f2bf(float f) {
    union { float f; unsigned u; } v; v.f = f;
    unsigned r = v.u + 0x7FFFu + ((v.u >> 16) & 1u);
    return (short)(r >> 16);
}
// bf16 -> f32
__device__ __forceinline__ float bf2f(short h) {
    union { unsigned u; float f; } v;
    v.u = ((unsigned)(unsigned short)h) << 16;
    return v.f;
}

__device__ __forceinline__ void cvt8(const float* __restrict__ s,
                                     short* __restrict__ d, int i) {
    const float4 a = *(const float4*)(s + i);
    const float4 b = *(const float4*)(s + i + 4);
    alignas(16) short h[8];
    h[0] = f2bf(a.x); h[1] = f2bf(a.y); h[2] = f2bf(a.z); h[3] = f2bf(a.w);
    h[4] = f2bf(b.x); h[5] = f2bf(b.y); h[6] = f2bf(b.z); h[7] = f2bf(b.w);
    *(uint4*)(d + i) = *(const uint4*)h;
}

// ---------------- fused f32 -> bf16 convert of all 4 weight tensors -------
__global__ __launch_bounds__(256) void cvt_weights(
    const float* __restrict__ s0, short* __restrict__ d0, int n0,
    const float* __restrict__ s1, short* __restrict__ d1, int n1,
    const float* __restrict__ s2, short* __restrict__ d2, int n2,
    const float* __restrict__ s3, short* __restrict__ d3, int n3)
{
    int i = (blockIdx.x * 256 + threadIdx.x) * 8;
    if (i < n0) { cvt8(s0, d0, i); return; }
    i -= n0;
    if (i < n1) { cvt8(s1, d1, i); return; }
    i -= n1;
    if (i < n2) { cvt8(s2, d2, i); return; }
    i -= n2;
    if (i < n3) { cvt8(s3, d3, i); return; }
}

// ---------------- LayerNorm: one block per row; f32 or bf16 out ----------
__global__ __launch_bounds__(256) void ln_kernel(
    const float* __restrict__ x, const float* __restrict__ w,
    const float* __restrict__ b, float* __restrict__ outf,
    short* __restrict__ outb)
{
    __shared__ float s1[256], s2[256];
    const int row = blockIdx.x;
    const int tid = threadIdx.x;
    const float* xr = x + (size_t)row * DMODEL;
    float v[4];
    float s = 0.f, sq = 0.f;
#pragma unroll
    for (int k = 0; k < 4; k++) {
        v[k] = xr[k * 256 + tid];
        s += v[k];
        sq += v[k] * v[k];
    }
    s1[tid] = s; s2[tid] = sq;
    __syncthreads();
    for (int off = 128; off > 0; off >>= 1) {
        if (tid < off) { s1[tid] += s1[tid + off]; s2[tid] += s2[tid + off]; }
        __syncthreads();
    }
    const float mu = s1[0] * (1.f / DMODEL);
    const float var = s2[0] * (1.f / DMODEL) - mu * mu;
    const float rstd = rsqrtf(var + 1e-5f);
#pragma unroll
    for (int k = 0; k < 4; k++) {
        const int i = k * 256 + tid;
        const float o = (v[k] - mu) * rstd * w[i] + b[i];
        if (outf) outf[(size_t)row * DMODEL + i] = o;
        if (outb) outb[(size_t)row * DMODEL + i] = f2bf(o);
    }
}

// ---------------- bf16 MFMA NT GEMM, 64 x (32*NJ) tile, XOR-swizzled LDS --
// C[M,N] = A[M,K] * W[N,K]^T, K per z-slice (blockIdx.z offsets A/W by z*K,
// C by z*csplit). 2x2 waves; each wave computes 32 x (16*NJ); NJ MFMA frags
// in N per row-frag -> 2*NJ MFMA per wave per k-iter (more per barrier).
// XOR swizzle: row r chunk c stored at phys chunk c ^ ((r>>1)&3) -> 2-way
// bank aliasing (free) for the quarter-wave ds_read_b128 pattern.
// MODE 0: f32 store (csplit)   MODE 2: f32 (. + resid)
// MODE 3: bf16 store           MODE 5: bf16 softplus(.+bias[n])
template<int NJ, int MODE>
__global__ __launch_bounds__(256) void gemm_mfma(
    const short* __restrict__ A, int lda,   // [M,lda] bf16
    const short* __restrict__ W, int ldw,   // [N,ldw] bf16
    float* __restrict__ Cf, short* __restrict__ Cb, int ldc,
    int M, int N, int K,
    const float* __restrict__ bias,
    const float* __restrict__ resid,
    size_t csplit)
{
    constexpr int BN = 32 * NJ;
    constexpr int HN = 16 * NJ;            // wave col span
    constexpr int WISS = BN / 64;          // W staging issues
    __shared__ alignas(16) short As[64 * 32];
    __shared__ alignas(16) short Ws[BN * 32];

    const int tid = threadIdx.x;
    const int lane = tid & 63;
    const int w = tid >> 6;
    const int wr = w >> 1, wc = w & 1;     // 2x2 waves
    const int row0 = blockIdx.y * 64;
    const int col0 = blockIdx.x * BN;
    const int kbeg = blockIdx.z * K;

    const int srow = tid >> 2;                              // staging row (0..63)
    const int skch = ((tid & 3) ^ ((srow >> 1) & 3)) * 8;   // swizzled k chunk

    f32x4 acc[2][NJ];
#pragma unroll
    for (int i = 0; i < 2; i++)
#pragma unroll
        for (int j = 0; j < NJ; j++) acc[i][j] = (f32x4)0.f;

    const int lrow = lane & 15;
    const int q = lane >> 4;               // logical chunk wanted by this lane

    for (int kt = kbeg; kt < kbeg + K; kt += 32) {
        __syncthreads();
        // stage A tile: 64 rows x 32 k (bf16) = 4 KB, one issue
        {
            const short* gp = A + (size_t)(row0 + srow) * lda + kt + skch;
            __builtin_amdgcn_global_load_lds(
                (const __attribute__((address_space(1))) void*)gp,
                (__attribute__((address_space(3))) void*)(As + tid * 8), 16, 0, 0);
        }
        // stage W tile (N guard for x_proj's 96-col case)
#pragma unroll
        for (int j = 0; j < WISS; j++) {
            const int wrow = col0 + j * 64 + srow;
            if (wrow < N) {
                const short* gp = W + (size_t)wrow * ldw + kt + skch;
                __builtin_amdgcn_global_load_lds(
                    (const __attribute__((address_space(1))) void*)gp,
                    (__attribute__((address_space(3))) void*)(Ws + j * 2048 + tid * 8),
                    16, 0, 0);
            }
        }
        __syncthreads();

        bf16x8 af[2], bfr[NJ];
#pragma unroll
        for (int i = 0; i < 2; i++) {
            const int R = wr * 32 + i * 16 + lrow;
            af[i] = *(const bf16x8*)&As[R * 32 + ((q ^ ((R >> 1) & 3)) * 8)];
        }
#pragma unroll
        for (int j = 0; j < NJ; j++) {
            const int R = wc * HN + j * 16 + lrow;
            bfr[j] = *(const bf16x8*)&Ws[R * 32 + ((q ^ ((R >> 1) & 3)) * 8)];
        }
#pragma unroll
        for (int i = 0; i < 2; i++)
#pragma unroll
            for (int j = 0; j < NJ; j++)
                acc[i][j] = __builtin_amdgcn_mfma_f32_16x16x32_bf16(
                    af[i], bfr[j], acc[i][j], 0, 0, 0);
    }

    if (MODE == 0 && csplit) Cf += blockIdx.z * csplit;

    // epilogue: C/D layout col=lane&15, row=(lane>>4)*4+reg
    const int rbase = row0 + wr * 32;
    const int cbase = col0 + wc * HN;
#pragma unroll
    for (int i = 0; i < 2; i++) {
#pragma unroll
        for (int j = 0; j < NJ; j++) {
            const int gcol = cbase + j * 16 + lrow;
            if (gcol < N) {
#pragma unroll
                for (int r = 0; r < 4; r++) {
                    const int grow = rbase + i * 16 + (lane >> 4) * 4 + r;
                    float v = acc[i][j][r];
                    if (MODE == 2) v += resid[(size_t)grow * ldc + gcol];
                    if (MODE == 5) v = softplusf(v + bias[gcol]);
                    if (MODE == 3 || MODE == 5) {
                        Cb[(size_t)grow * ldc + gcol] = f2bf(v);
                    } else {
                        Cf[(size_t)grow * ldc + gcol] = v;
                    }
                }
            }
        }
    }
}

// ---------------- x_proj split-K combine: dbl = sum of partials ----------
__global__ __launch_bounds__(256) void combine_xproj(
    const float* __restrict__ part,   // [XSPLIT][LSEQ*RPROJ]
    float* __restrict__ dbl, short* __restrict__ dblb)
{
    const int i = (blockIdx.x * 256 + threadIdx.x) * 4;
    const int S = LSEQ * RPROJ;
    float4 v = *(const float4*)(part + i);
#pragma unroll
    for (int s = 1; s < XSPLIT; s++) {
        const float4 p = *(const float4*)(part + s * S + i);
        v.x += p.x; v.y += p.y; v.z += p.z; v.w += p.w;
    }
    *(float4*)(dbl + i) = v;
    alignas(8) short h[4] = {f2bf(v.x), f2bf(v.y), f2bf(v.z), f2bf(v.w)};
    *(unsigned long long*)(dblb + i) = *(const unsigned long long*)h;
}

// ---------------- Causal depthwise conv (k=4) + bias + silu --------------
// 8 channels per thread, bf16x8 vector loads/stores.
__global__ __launch_bounds__(256) void conv_silu_kernel(
    const short* __restrict__ xzb, const float* __restrict__ cw,
    const float* __restrict__ cb, short* __restrict__ xcb)
{
    const int g = blockIdx.x * 256 + threadIdx.x;   // over L * DINNER/8
    const int t = g >> 8;             // DINNER/8 = 256 groups per t
    const int c0 = (g & 255) * 8;
    float acc[8];
#pragma unroll
    for (int j = 0; j < 8; j++) acc[j] = cb[c0 + j];
#pragma unroll
    for (int k = 0; k < DCONV; k++) {
        const int tt = t - (DCONV - 1) + k;
        if (tt >= 0) {
            const bf16x8 v = *(const bf16x8*)(xzb + (size_t)tt * (2 * DINNER) + c0);
#pragma unroll
            for (int j = 0; j < 8; j++)
                acc[j] += bf2f(v[j]) * cw[(c0 + j) * DCONV + k];
        }
    }
    alignas(16) short h[8];
#pragma unroll
    for (int j = 0; j < 8; j++) h[j] = f2bf(siluf(acc[j]));
    *(uint4*)(xcb + (size_t)t * DINNER + c0) = *(const uint4*)h;
}

// ============ Chunked selective scan ============
// pass1: chunk-local scan from h=0; explicit next-t prefetch hides latency.
__global__ __launch_bounds__(256) void scan_pass1(
    const short* __restrict__ dtb,   // [L, DINNER] bf16
    const short* __restrict__ xcb,   // [L, DINNER] bf16
    const float* __restrict__ dbl,   // [L, RPROJ] f32
    const float* __restrict__ A_log,
    float* __restrict__ S,           // [NCHUNK][DSTATE][DINNER]
    float* __restrict__ sumdt)       // [NCHUNK][DINNER]
{
    const int e = blockIdx.x * 256 + threadIdx.x;
    const int c = blockIdx.y;
    float a[DSTATE];
#pragma unroll
    for (int n = 0; n < DSTATE; n++) a[n] = -__expf(A_log[(size_t)e * DSTATE + n]);
    float h[DSTATE];
#pragma unroll
    for (int n = 0; n < DSTATE; n++) h[n] = 0.f;
    float sd = 0.f;

    __shared__ float sBC[CHUNK][32];
    for (int i = threadIdx.x; i < CHUNK * 32; i += 256) {
        const int tl = i >> 5, j = i & 31;
        sBC[tl][j] = dbl[(size_t)(c * CHUNK + tl) * RPROJ + DTRANK + j];
    }
    __syncthreads();

    const size_t rb = (size_t)c * CHUNK * DINNER + e;
    short dt_c = dtb[rb], xc_c = xcb[rb];
#pragma unroll
    for (int tl = 0; tl < CHUNK; tl++) {
        short dt_n = 0, xc_n = 0;
        if (tl + 1 < CHUNK) {
            dt_n = dtb[rb + (size_t)(tl + 1) * DINNER];
            xc_n = xcb[rb + (size_t)(tl + 1) * DINNER];
        }
        const float dtv = bf2f(dt_c);
        const float du = dtv * bf2f(xc_c);
        sd += dtv;
#pragma unroll
        for (int n = 0; n < DSTATE; n++) {
            const float dA = __expf(dtv * a[n]);
            h[n] = dA * h[n] + du * sBC[tl][n];
        }
        dt_c = dt_n; xc_c = xc_n;
    }
    sumdt[(size_t)c * DINNER + e] = sd;
#pragma unroll
    for (int n = 0; n < DSTATE; n++)
        S[((size_t)c * DSTATE + n) * DINNER + e] = h[n];
}

// pass2: sequential combine over chunks; rewrite S in place with carry-IN.
__global__ __launch_bounds__(256) void scan_pass2(
    const float* __restrict__ A_log,
    const float* __restrict__ sumdt,
    float* __restrict__ S)
{
    const int idx = blockIdx.x * 256 + threadIdx.x;
    const int e = idx & (DINNER - 1);
    const int n = idx >> 11;
    const float a = -__expf(A_log[(size_t)e * DSTATE + n]);
    float H = 0.f;
    for (int c = 0; c < NCHUNK; c++) {
        const size_t off = ((size_t)c * DSTATE + n) * DINNER + e;
        const float tmp = S[off];
        S[off] = H;
        const float P = __expf(a * sumdt[(size_t)c * DINNER + e]);
        H = P * H + tmp;
    }
}

// pass3: seeded chunk-local scan -> gated y (bf16 for out_proj)
__global__ __launch_bounds__(256) void scan_pass3(
    const short* __restrict__ dtb,
    const short* __restrict__ xcb,
    const float* __restrict__ dbl,
    const short* __restrict__ xzb,   // z at cols DINNER.. (bf16)
    const float* __restrict__ A_log,
    const float* __restrict__ Dp,
    const float* __restrict__ S,
    short* __restrict__ yb)
{
    const int e = blockIdx.x * 256 + threadIdx.x;
    const int c = blockIdx.y;
    float a[DSTATE];
#pragma unroll
    for (int n = 0; n < DSTATE; n++) a[n] = -__expf(A_log[(size_t)e * DSTATE + n]);
    float h[DSTATE];
#pragma unroll
    for (int n = 0; n < DSTATE; n++)
        h[n] = S[((size_t)c * DSTATE + n) * DINNER + e];
    const float dskip = Dp[e];

    __shared__ float sBC[CHUNK][32];
    for (int i = threadIdx.x; i < CHUNK * 32; i += 256) {
        const int tl = i >> 5, j = i & 31;
        sBC[tl][j] = dbl[(size_t)(c * CHUNK + tl) * RPROJ + DTRANK + j];
    }
    __syncthreads();

    const size_t rb = (size_t)c * CHUNK * DINNER + e;
    const size_t zb = (size_t)c * CHUNK * (2 * DINNER) + DINNER + e;
    short dt_c = dtb[rb], xc_c = xcb[rb], z_c = xzb[zb];
#pragma unroll
    for (int tl = 0; tl < CHUNK; tl++) {
        short dt_n = 0, xc_n = 0, z_n = 0;
        if (tl + 1 < CHUNK) {
            dt_n = dtb[rb + (size_t)(tl + 1) * DINNER];
            xc_n = xcb[rb + (size_t)(tl + 1) * DINNER];
            z_n = xzb[zb + (size_t)(tl + 1) * (2 * DINNER)];
        }
        const float dtv = bf2f(dt_c);
        const float xcv = bf2f(xc_c);
        const float du = dtv * xcv;
        float yv = 0.f;
#pragma unroll
        for (int n = 0; n < DSTATE; n++) {
            const float dA = __expf(dtv * a[n]);
            h[n] = dA * h[n] + du * sBC[tl][n];
            yv += h[n] * sBC[tl][16 + n];
        }
        yv = (yv + xcv * dskip) * siluf(bf2f(z_c));
        yb[rb + (size_t)tl * DINNER] = f2bf(yv);
        dt_c = dt_n; xc_c = xc_n; z_c = z_n;
    }
}

extern "C" void kernel_launch(void* const* d_in, const int* in_sizes, int n_in,
                              void* d_out, int out_size, void* d_ws, size_t ws_size,
                              hipStream_t stream) {
    const float* x_in   = (const float*)d_in[0];
    const float* ln_w   = (const float*)d_in[1];
    const float* ln_b   = (const float*)d_in[2];
    const float* in_w   = (const float*)d_in[3];
    const float* conv_w = (const float*)d_in[4];
    const float* conv_b = (const float*)d_in[5];
    const float* xp_w   = (const float*)d_in[6];
    const float* dtp_w  = (const float*)d_in[7];
    const float* dtp_b  = (const float*)d_in[8];
    const float* A_log  = (const float*)d_in[9];
    const float* D_skip = (const float*)d_in[10];
    const float* out_w  = (const float*)d_in[11];
    const float* nf_w   = (const float*)d_in[12];
    const float* nf_b   = (const float*)d_in[13];
    float* out = (float*)d_out;

    float* w = (float*)d_ws;
    float* buf_x = w; w += (size_t)LSEQ * DMODEL;              // residual stream (f32)
    float* dbl   = w; w += (size_t)LSEQ * RPROJ;               // x_proj out (f32)
    float* xpart = w; w += (size_t)XSPLIT * LSEQ * RPROJ;      // x_proj split-K partials
    float* Sbuf  = w; w += (size_t)NCHUNK * DSTATE * DINNER;   // chunk summaries
    float* sumdt = w; w += (size_t)NCHUNK * DINNER;
    // bf16 buffers (sized in float units, 2 shorts per float)
    short* h_bf    = (short*)w; w += (size_t)LSEQ * DMODEL / 2;
    short* xz_bf   = (short*)w; w += (size_t)LSEQ * 2 * DINNER / 2;
    short* xc_bf   = (short*)w; w += (size_t)LSEQ * DINNER / 2;
    short* dt_bf   = (short*)w; w += (size_t)LSEQ * DINNER / 2;
    short* y_bf    = (short*)w; w += (size_t)LSEQ * DINNER / 2;
    short* dbl_bf  = (short*)w; w += (size_t)LSEQ * RPROJ / 2 + 1;
    short* in_w_bf  = (short*)w; w += (size_t)2 * (2 * DINNER) * DMODEL / 2;
    short* xp_w_bf  = (short*)w; w += (size_t)2 * RPROJ * DINNER / 2;
    short* dtp_w_bf = (short*)w; w += (size_t)2 * DINNER * DTRANK / 2;
    short* out_w_bf = (short*)w; w += (size_t)2 * DMODEL * DINNER / 2;

    // fused weight conversion (all layers, all 4 tensors, one dispatch)
    {
        const int n1 = 2 * (2 * DINNER) * DMODEL;   // 8388608
        const int n2 = 2 * RPROJ * DINNER;          // 393216
        const int n3 = 2 * DMODEL * DINNER;         // 4194304
        const int n4 = 2 * DINNER * DTRANK;         // 262144
        const int total = n1 + n2 + n3 + n4;        // 13238272
        cvt_weights<<<dim3(total / (256 * 8)), dim3(256), 0, stream>>>(
            in_w, in_w_bf, n1, xp_w, xp_w_bf, n2,
            out_w, out_w_bf, n3, dtp_w, dtp_w_bf, n4);
    }

    for (int layer = 0; layer < 2; layer++) {
        const float* resid_src = (layer == 0) ? x_in : buf_x;
        // 1. LayerNorm -> bf16
        ln_kernel<<<dim3(LSEQ), dim3(256), 0, stream>>>(
            resid_src, ln_w + layer * DMODEL, ln_b + layer * DMODEL,
            nullptr, h_bf);
        // 2. in_proj (MFMA 64x128, bf16 out): xz_bf[L,4096] = h * in_w^T
        gemm_mfma<4, 3><<<dim3((2 * DINNER) / 128, LSEQ / 64), dim3(256), 0, stream>>>(
            h_bf, DMODEL, in_w_bf + (size_t)layer * 2 * DINNER * DMODEL, DMODEL,
            nullptr, xz_bf, 2 * DINNER, LSEQ, 2 * DINNER, DMODEL, nullptr, nullptr, 0);
        // 3. conv + silu -> bf16 (vectorized)
        conv_silu_kernel<<<dim3((LSEQ * DINNER / 8) / 256), dim3(256), 0, stream>>>(
            xz_bf, conv_w + (size_t)layer * DINNER * DCONV, conv_b + layer * DINNER,
            xc_bf);
        // 4. x_proj (MFMA 64x64, split-K=4 -> partials) + combine
        gemm_mfma<2, 0><<<dim3(2, LSEQ / 64, XSPLIT), dim3(256), 0, stream>>>(
            xc_bf, DINNER, xp_w_bf + (size_t)layer * RPROJ * DINNER, DINNER,
            xpart, nullptr, RPROJ, LSEQ, RPROJ, DINNER / XSPLIT, nullptr, nullptr,
            (size_t)LSEQ * RPROJ);
        combine_xproj<<<dim3((LSEQ * RPROJ / 4) / 256), dim3(256), 0, stream>>>(
            xpart, dbl, dbl_bf);
        // 5. dt_proj (MFMA 64x128, softplus+bias -> bf16): dt_bf[L,2048], K=64
        gemm_mfma<4, 5><<<dim3(DINNER / 128, LSEQ / 64), dim3(256), 0, stream>>>(
            dbl_bf, RPROJ, dtp_w_bf + (size_t)layer * DINNER * DTRANK, DTRANK,
            nullptr, dt_bf, DINNER, LSEQ, DINNER, DTRANK,
            dtp_b + layer * DINNER, nullptr, 0);
        // 6. chunked selective scan (+ skip + z-gate) -> y_bf
        const float* Al = A_log + (size_t)layer * DINNER * DSTATE;
        scan_pass1<<<dim3(DINNER / 256, NCHUNK), dim3(256), 0, stream>>>(
            dt_bf, xc_bf, dbl, Al, Sbuf, sumdt);
        scan_pass2<<<dim3((DINNER * DSTATE) / 256), dim3(256), 0, stream>>>(
            Al, sumdt, Sbuf);
        scan_pass3<<<dim3(DINNER / 256, NCHUNK), dim3(256), 0, stream>>>(
            dt_bf, xc_bf, dbl, xz_bf, Al, D_skip + layer * DINNER, Sbuf, y_bf);
        // 7. out_proj (MFMA 64x64) + residual -> buf_x f32
        gemm_mfma<2, 2><<<dim3(DMODEL / 64, LSEQ / 64), dim3(256), 0, stream>>>(
            y_bf, DINNER, out_w_bf + (size_t)layer * DMODEL * DINNER, DINNER,
            buf_x, nullptr, DMODEL, LSEQ, DMODEL, DINNER, nullptr, resid_src, 0);
    }
    // final LayerNorm -> d_out (f32)
    ln_kernel<<<dim3(LSEQ), dim3(256), 0, stream>>>(buf_x, nf_w, nf_b, out, nullptr);
}